// Round 1
// baseline (3694.759 us; speedup 1.0000x reference)
//
#include <hip/hip_runtime.h>
#include <stdint.h>

#define N_NODES 50000
#define DIN     512
#define DOUT    128
#define NSUP    2
#define NCOLS   (NSUP * DOUT)   // 256
#define EDGES   800000

// ---- JAX threefry2x32, key = jax.random.key(42) -> key data (0, 42) ----
// PRNG_VARIANT: 0 = partitionable, bits = o0 ^ o1   (primary hypothesis)
//               1 = partitionable, bits = o0
//               2 = partitionable, bits = o1
//               3 = original (non-partitionable) split-iota mode
#define PRNG_VARIANT 0

__device__ __forceinline__ uint32_t rotl32(uint32_t v, uint32_t d) {
  return (v << d) | (v >> (32u - d));
}

__device__ __forceinline__ void threefry2x32(uint32_t x0, uint32_t x1,
                                             uint32_t& o0, uint32_t& o1) {
  const uint32_t ks0 = 0u;
  const uint32_t ks1 = 42u;
  const uint32_t ks2 = 0u ^ 42u ^ 0x1BD11BDAu;
  x0 += ks0; x1 += ks1;
#define TF_R(r) { x0 += x1; x1 = rotl32(x1, (r)); x1 ^= x0; }
  TF_R(13) TF_R(15) TF_R(26) TF_R(6)
  x0 += ks1; x1 += ks2 + 1u;
  TF_R(17) TF_R(29) TF_R(16) TF_R(24)
  x0 += ks2; x1 += ks0 + 2u;
  TF_R(13) TF_R(15) TF_R(26) TF_R(6)
  x0 += ks0; x1 += ks1 + 3u;
  TF_R(17) TF_R(29) TF_R(16) TF_R(24)
  x0 += ks1; x1 += ks2 + 4u;
  TF_R(13) TF_R(15) TF_R(26) TF_R(6)
  x0 += ks2; x1 += ks0 + 5u;
#undef TF_R
  o0 = x0; o1 = x1;
}

__device__ __forceinline__ bool keep_mask(uint32_t idx) {
  uint32_t o0, o1, bits;
#if PRNG_VARIANT == 3
  const uint32_t HALF = (uint32_t)(N_NODES * DIN) / 2u;  // 12,800,000
  if (idx < HALF) { threefry2x32(idx, idx + HALF, o0, o1); bits = o0; }
  else            { threefry2x32(idx - HALF, idx, o0, o1); bits = o1; }
#else
  threefry2x32(0u, idx, o0, o1);
#if PRNG_VARIANT == 0
  bits = o0 ^ o1;
#elif PRNG_VARIANT == 1
  bits = o0;
#else
  bits = o1;
#endif
#endif
  float u = __uint_as_float((bits >> 9) | 0x3F800000u) - 1.0f;
  return u < 0.5f;
}

// ---- Fused dropout + GEMM: pre[s][n][o] = sum_k xd[n][k] * w[s][k][o] ----
// Block: 256 threads = 4 waves. BM=64 rows, each wave owns 64 of the 256
// output columns (cols = wave*64 .. +63 -> support s = wave>>1, obase=(wave&1)*64).
// A tile staged in LDS (dropout fused); B read from global (L2-resident, 512KB)
// with wave-uniform broadcast float4 loads.
#define BM 64
#define KC 128

__global__ __launch_bounds__(256, 2) void gemm_dropout(
    const float* __restrict__ x, const float* __restrict__ w,
    float* __restrict__ pre) {
  __shared__ float As[BM][KC + 1];   // +1 pad: A-read banks = (r+k)&31, 2-way = free
  const int t  = threadIdx.x;
  const int r  = t & 63;
  const int wv = t >> 6;             // wave id 0..3
  const int m0 = blockIdx.x * BM;
  const int row = m0 + r;
  const int s   = wv >> 1;
  const int ob  = (wv & 1) * 64;

  float acc[64];
#pragma unroll
  for (int j = 0; j < 64; ++j) acc[j] = 0.f;

  for (int kc = 0; kc < DIN; kc += KC) {
    __syncthreads();
    // stage 64x128 A elems: 2048 float4, 8 per thread, coalesced; dropout fused
#pragma unroll
    for (int i = 0; i < 8; ++i) {
      int idx4 = i * 256 + t;        // 0..2047
      int rr   = idx4 >> 5;          // row in tile (32 float4 per row)
      int k4   = idx4 & 31;
      int grow = m0 + rr;
      float4 v = make_float4(0.f, 0.f, 0.f, 0.f);
      if (grow < N_NODES) {
        v = *reinterpret_cast<const float4*>(x + (size_t)grow * DIN + kc + k4 * 4);
        uint32_t base = (uint32_t)(grow * DIN + kc + k4 * 4);
        float* vp = &v.x;
#pragma unroll
        for (int q = 0; q < 4; ++q)
          vp[q] = keep_mask(base + q) ? vp[q] * 2.0f : 0.f;
      }
      // scalar stores (padded row start isn't 16B aligned)
      As[rr][k4 * 4 + 0] = v.x;
      As[rr][k4 * 4 + 1] = v.y;
      As[rr][k4 * 4 + 2] = v.z;
      As[rr][k4 * 4 + 3] = v.w;
    }
    __syncthreads();

#pragma unroll 4
    for (int k = 0; k < KC; ++k) {
      float a = As[r][k];
      const float4* b4 = reinterpret_cast<const float4*>(
          w + ((size_t)(s * DIN + kc + k)) * DOUT + ob);
#pragma unroll
      for (int jb = 0; jb < 16; ++jb) {
        float4 b = b4[jb];
        acc[jb * 4 + 0] += a * b.x;
        acc[jb * 4 + 1] += a * b.y;
        acc[jb * 4 + 2] += a * b.z;
        acc[jb * 4 + 3] += a * b.w;
      }
    }
  }

  if (row < N_NODES) {
    float* dst = pre + ((size_t)s * N_NODES + row) * DOUT + ob;
#pragma unroll
    for (int jb = 0; jb < 16; ++jb) {
      float4 v = make_float4(acc[jb * 4 + 0], acc[jb * 4 + 1],
                             acc[jb * 4 + 2], acc[jb * 4 + 3]);
      reinterpret_cast<float4*>(dst)[jb] = v;
    }
  }
}

// ---- SpMM scatter: out[s][row] += val * pre[s][col], 32 lanes per edge ----
__global__ __launch_bounds__(256) void spmm_atomic(
    const int* __restrict__ rows, const int* __restrict__ cols,
    const float* __restrict__ vals, const float* __restrict__ pre,
    float* __restrict__ out) {
  int gid = blockIdx.x * 256 + threadIdx.x;
  int e = gid >> 5;                  // flat edge id in [0, 2E)
  int l = gid & 31;
  if (e >= 2 * EDGES) return;
  int s = (e >= EDGES) ? 1 : 0;
  int rr = rows[e];
  int cc = cols[e];
  float v = vals[e];
  const float4 h = *reinterpret_cast<const float4*>(
      pre + ((size_t)s * N_NODES + cc) * DOUT + l * 4);
  float* o = out + ((size_t)s * N_NODES + rr) * DOUT + l * 4;
  atomicAdd(o + 0, v * h.x);
  atomicAdd(o + 1, v * h.y);
  atomicAdd(o + 2, v * h.z);
  atomicAdd(o + 3, v * h.w);
}

// ---- ReLU in place ----
__global__ __launch_bounds__(256) void relu_k(float* __restrict__ out, int n4) {
  int i = blockIdx.x * 256 + threadIdx.x;
  if (i < n4) {
    float4* p = reinterpret_cast<float4*>(out) + i;
    float4 v = *p;
    v.x = fmaxf(v.x, 0.f);
    v.y = fmaxf(v.y, 0.f);
    v.z = fmaxf(v.z, 0.f);
    v.w = fmaxf(v.w, 0.f);
    *p = v;
  }
}

extern "C" void kernel_launch(void* const* d_in, const int* in_sizes, int n_in,
                              void* d_out, int out_size, void* d_ws, size_t ws_size,
                              hipStream_t stream) {
  const float* x    = (const float*)d_in[0];
  const float* w    = (const float*)d_in[1];
  const int*   rows = (const int*)d_in[2];
  const int*   cols = (const int*)d_in[3];
  const float* vals = (const float*)d_in[4];
  float* out = (float*)d_out;
  float* pre = (float*)d_ws;   // [2][50000][128] fp32 = 51.2 MB

  if (ws_size < (size_t)NSUP * N_NODES * DOUT * sizeof(float)) return; // loud fail

  // zero output (atomics accumulate into it)
  hipMemsetAsync(d_out, 0, (size_t)out_size * sizeof(float), stream);

  const int mblocks = (N_NODES + BM - 1) / BM;            // 782
  gemm_dropout<<<mblocks, 256, 0, stream>>>(x, w, pre);

  const int sp_blocks = (2 * EDGES * 32) / 256;           // 200000
  spmm_atomic<<<sp_blocks, 256, 0, stream>>>(rows, cols, vals, pre, out);

  const int n4 = out_size / 4;                            // 3.2M float4
  relu_k<<<(n4 + 255) / 256, 256, 0, stream>>>(out, n4);
}

// Round 2
// 1666.533 us; speedup vs baseline: 2.2170x; 2.2170x over previous
//
#include <hip/hip_runtime.h>
#include <stdint.h>

#define N_NODES 50000
#define DIN     512
#define DOUT    128
#define NSUP    2
#define EDGES   800000
#define NROWS   (NSUP * N_NODES)   // 100000 output rows total

// ---- JAX threefry2x32, key = jax.random.key(42) -> key data (0, 42) ----
// Verified round 1: partitionable threefry, bits = o0 ^ o1.
__device__ __forceinline__ uint32_t rotl32(uint32_t v, uint32_t d) {
  return (v << d) | (v >> (32u - d));
}

__device__ __forceinline__ void threefry2x32(uint32_t x0, uint32_t x1,
                                             uint32_t& o0, uint32_t& o1) {
  const uint32_t ks0 = 0u;
  const uint32_t ks1 = 42u;
  const uint32_t ks2 = 0u ^ 42u ^ 0x1BD11BDAu;
  x0 += ks0; x1 += ks1;
#define TF_R(r) { x0 += x1; x1 = rotl32(x1, (r)); x1 ^= x0; }
  TF_R(13) TF_R(15) TF_R(26) TF_R(6)
  x0 += ks1; x1 += ks2 + 1u;
  TF_R(17) TF_R(29) TF_R(16) TF_R(24)
  x0 += ks2; x1 += ks0 + 2u;
  TF_R(13) TF_R(15) TF_R(26) TF_R(6)
  x0 += ks0; x1 += ks1 + 3u;
  TF_R(17) TF_R(29) TF_R(16) TF_R(24)
  x0 += ks1; x1 += ks2 + 4u;
  TF_R(13) TF_R(15) TF_R(26) TF_R(6)
  x0 += ks2; x1 += ks0 + 5u;
#undef TF_R
  o0 = x0; o1 = x1;
}

__device__ __forceinline__ bool keep_mask(uint32_t idx) {
  uint32_t o0, o1;
  threefry2x32(0u, idx, o0, o1);
  uint32_t bits = o0 ^ o1;
  float u = __uint_as_float((bits >> 9) | 0x3F800000u) - 1.0f;
  return u < 0.5f;
}

// pack two fp32 -> bf16x2 (round to nearest even), lo = first element
__device__ __forceinline__ uint32_t pack_bf16x2(float a, float b) {
  uint32_t ua = __float_as_uint(a), ub = __float_as_uint(b);
  ua += 0x7fffu + ((ua >> 16) & 1u);
  ub += 0x7fffu + ((ub >> 16) & 1u);
  return (ua >> 16) | (ub & 0xffff0000u);
}

// ---- Fused dropout + GEMM: pre16[s][n][o] = bf16( sum_k xd[n][k]*w[s][k][o] )
#define BM 64
#define KC 128

__global__ __launch_bounds__(256, 2) void gemm_dropout(
    const float* __restrict__ x, const float* __restrict__ w,
    uint32_t* __restrict__ pre16) {
  __shared__ float As[BM][KC + 1];
  const int t  = threadIdx.x;
  const int r  = t & 63;
  const int wv = t >> 6;
  const int m0 = blockIdx.x * BM;
  const int row = m0 + r;
  const int s   = wv >> 1;
  const int ob  = (wv & 1) * 64;

  float acc[64];
#pragma unroll
  for (int j = 0; j < 64; ++j) acc[j] = 0.f;

  for (int kc = 0; kc < DIN; kc += KC) {
    __syncthreads();
#pragma unroll
    for (int i = 0; i < 8; ++i) {
      int idx4 = i * 256 + t;
      int rr   = idx4 >> 5;
      int k4   = idx4 & 31;
      int grow = m0 + rr;
      float4 v = make_float4(0.f, 0.f, 0.f, 0.f);
      if (grow < N_NODES) {
        v = *reinterpret_cast<const float4*>(x + (size_t)grow * DIN + kc + k4 * 4);
        uint32_t base = (uint32_t)(grow * DIN + kc + k4 * 4);
        float* vp = &v.x;
#pragma unroll
        for (int q = 0; q < 4; ++q)
          vp[q] = keep_mask(base + q) ? vp[q] * 2.0f : 0.f;
      }
      As[rr][k4 * 4 + 0] = v.x;
      As[rr][k4 * 4 + 1] = v.y;
      As[rr][k4 * 4 + 2] = v.z;
      As[rr][k4 * 4 + 3] = v.w;
    }
    __syncthreads();

#pragma unroll 4
    for (int k = 0; k < KC; ++k) {
      float a = As[r][k];
      const float4* b4 = reinterpret_cast<const float4*>(
          w + ((size_t)(s * DIN + kc + k)) * DOUT + ob);
#pragma unroll
      for (int jb = 0; jb < 16; ++jb) {
        float4 b = b4[jb];
        acc[jb * 4 + 0] += a * b.x;
        acc[jb * 4 + 1] += a * b.y;
        acc[jb * 4 + 2] += a * b.z;
        acc[jb * 4 + 3] += a * b.w;
      }
    }
  }

  if (row < N_NODES) {
    uint32_t* dst = pre16 + ((size_t)(s * N_NODES + row) * DOUT + ob) / 2;
#pragma unroll
    for (int j = 0; j < 32; ++j)
      dst[j] = pack_bf16x2(acc[2 * j], acc[2 * j + 1]);
  }
}

// ---- CSR build ----
__global__ __launch_bounds__(256) void count_k(
    const int* __restrict__ rows, int* __restrict__ cnt) {
  int i = blockIdx.x * 256 + threadIdx.x;
  if (i >= NSUP * EDGES) return;
  int s = (i >= EDGES) ? 1 : 0;
  atomicAdd(cnt + s * N_NODES + rows[i], 1);
}

#define SCAN_T 1024
__global__ __launch_bounds__(SCAN_T) void scan_k(
    const int* __restrict__ cnt, int* __restrict__ row_start,
    int* __restrict__ cursor) {
  __shared__ int sums[SCAN_T];
  const int t = threadIdx.x;
  const int n = NROWS;
  const int chunk = (n + SCAN_T - 1) / SCAN_T;   // 98
  int lo = t * chunk;
  int hi = lo + chunk; if (hi > n) hi = n; if (lo > n) lo = n;
  int s = 0;
  for (int i = lo; i < hi; ++i) s += cnt[i];
  sums[t] = s;
  __syncthreads();
  for (int d = 1; d < SCAN_T; d <<= 1) {
    int v = sums[t];
    int add = (t >= d) ? sums[t - d] : 0;
    __syncthreads();
    sums[t] = v + add;
    __syncthreads();
  }
  int prefix = (t == 0) ? 0 : sums[t - 1];
  for (int i = lo; i < hi; ++i) {
    row_start[i] = prefix;
    cursor[i]    = prefix;
    prefix += cnt[i];
  }
  if (t == SCAN_T - 1) row_start[n] = prefix;   // = 2E
}

__global__ __launch_bounds__(256) void scatter_k(
    const int* __restrict__ rows, const int* __restrict__ cols,
    const float* __restrict__ vals, int* __restrict__ cursor,
    int* __restrict__ csr_col, float* __restrict__ csr_val) {
  int i = blockIdx.x * 256 + threadIdx.x;
  if (i >= NSUP * EDGES) return;
  int s = (i >= EDGES) ? 1 : 0;
  int slot = atomicAdd(cursor + s * N_NODES + rows[i], 1);
  csr_col[slot] = s * N_NODES + cols[i];   // global row index into pre16
  csr_val[slot] = vals[i];
}

// ---- Pull SpMM + ReLU: one wave per output row, lane owns cols {2l, 2l+1}
__global__ __launch_bounds__(256) void spmm_pull(
    const int* __restrict__ row_start, const int* __restrict__ csr_col,
    const float* __restrict__ csr_val, const uint32_t* __restrict__ pre16,
    float* __restrict__ out) {
  int rid  = blockIdx.x * 4 + (threadIdx.x >> 6);
  int lane = threadIdx.x & 63;
  if (rid >= NROWS) return;
  int beg = row_start[rid];
  int end = row_start[rid + 1];
  float a0 = 0.f, a1 = 0.f;
  for (int j = beg; j < end; ++j) {
    int   c = csr_col[j];          // broadcast (wave-uniform)
    float v = csr_val[j];
    uint32_t p = pre16[(size_t)c * (DOUT / 2) + lane];
    float p0 = __uint_as_float(p << 16);
    float p1 = __uint_as_float(p & 0xffff0000u);
    a0 += v * p0;
    a1 += v * p1;
  }
  float2 o = make_float2(fmaxf(a0, 0.f), fmaxf(a1, 0.f));
  *reinterpret_cast<float2*>(out + (size_t)rid * DOUT + 2 * lane) = o;
}

extern "C" void kernel_launch(void* const* d_in, const int* in_sizes, int n_in,
                              void* d_out, int out_size, void* d_ws, size_t ws_size,
                              hipStream_t stream) {
  const float* x    = (const float*)d_in[0];
  const float* w    = (const float*)d_in[1];
  const int*   rows = (const int*)d_in[2];
  const int*   cols = (const int*)d_in[3];
  const float* vals = (const float*)d_in[4];
  float* out = (float*)d_out;

  // ws layout (4-byte units)
  uint32_t* pre16     = (uint32_t*)d_ws;                     // 6,400,000 u32
  int*      cnt       = (int*)(pre16 + 6400000);             // 100,000
  int*      row_start = cnt + 100000;                        // 100,001
  int*      cursor    = row_start + 100004;                  // 100,000 (pad 3)
  int*      csr_col   = cursor + 100000;                     // 1,600,000
  float*    csr_val   = (float*)(csr_col + 1600000);         // 1,600,000
  size_t need = ((size_t)6400000 + 100000 + 100004 + 100000 + 1600000 + 1600000) * 4;
  if (ws_size < need) return;  // loud fail

  hipMemsetAsync(cnt, 0, 100000 * sizeof(int), stream);

  const int mblocks = (N_NODES + BM - 1) / BM;               // 782
  gemm_dropout<<<mblocks, 256, 0, stream>>>(x, w, pre16);

  const int eblocks = (NSUP * EDGES + 255) / 256;            // 6250
  count_k<<<eblocks, 256, 0, stream>>>(rows, cnt);
  scan_k<<<1, SCAN_T, 0, stream>>>(cnt, row_start, cursor);
  scatter_k<<<eblocks, 256, 0, stream>>>(rows, cols, vals, cursor, csr_col, csr_val);

  const int rblocks = (NROWS + 3) / 4;                       // 25000
  spmm_pull<<<rblocks, 256, 0, stream>>>(row_start, csr_col, csr_val, pre16, out);
}

// Round 3
// 366.217 us; speedup vs baseline: 10.0890x; 4.5507x over previous
//
#include <hip/hip_runtime.h>
#include <stdint.h>

#define N_NODES 50000
#define DIN     512
#define DOUT    128
#define NSUP    2
#define EDGES   800000
#define NROWS   (NSUP * N_NODES)   // 100000

typedef __attribute__((ext_vector_type(8))) short short8;
typedef __attribute__((ext_vector_type(4))) float f32x4;

// ---- JAX threefry2x32, key(42) -> (0,42); partitionable, bits = o0^o1 (verified R1) ----
__device__ __forceinline__ uint32_t rotl32(uint32_t v, uint32_t d) {
  return (v << d) | (v >> (32u - d));
}

__device__ __forceinline__ void threefry2x32(uint32_t x0, uint32_t x1,
                                             uint32_t& o0, uint32_t& o1) {
  const uint32_t ks0 = 0u;
  const uint32_t ks1 = 42u;
  const uint32_t ks2 = 0u ^ 42u ^ 0x1BD11BDAu;
  x0 += ks0; x1 += ks1;
#define TF_R(r) { x0 += x1; x1 = rotl32(x1, (r)); x1 ^= x0; }
  TF_R(13) TF_R(15) TF_R(26) TF_R(6)
  x0 += ks1; x1 += ks2 + 1u;
  TF_R(17) TF_R(29) TF_R(16) TF_R(24)
  x0 += ks2; x1 += ks0 + 2u;
  TF_R(13) TF_R(15) TF_R(26) TF_R(6)
  x0 += ks0; x1 += ks1 + 3u;
  TF_R(17) TF_R(29) TF_R(16) TF_R(24)
  x0 += ks1; x1 += ks2 + 4u;
  TF_R(13) TF_R(15) TF_R(26) TF_R(6)
  x0 += ks2; x1 += ks0 + 5u;
#undef TF_R
  o0 = x0; o1 = x1;
}

__device__ __forceinline__ bool keep_mask(uint32_t idx) {
  uint32_t o0, o1;
  threefry2x32(0u, idx, o0, o1);
  uint32_t bits = o0 ^ o1;
  float u = __uint_as_float((bits >> 9) | 0x3F800000u) - 1.0f;
  return u < 0.5f;
}

__device__ __forceinline__ uint32_t pack_bf16x2(float a, float b) {
  uint32_t ua = __float_as_uint(a), ub = __float_as_uint(b);
  ua += 0x7fffu + ((ua >> 16) & 1u);
  ub += 0x7fffu + ((ub >> 16) & 1u);
  return (ua >> 16) | (ub & 0xffff0000u);
}

__device__ __forceinline__ uint32_t bf16rne(float f) {
  uint32_t u = __float_as_uint(f);
  u += 0x7fffu + ((u >> 16) & 1u);
  return u >> 16;
}

// ---- W [2][512][128] fp32 -> B16t [256 cols][512 k] bf16 (col = s*128+o) ----
__global__ __launch_bounds__(256) void wcvt(const float* __restrict__ w,
                                            unsigned short* __restrict__ b16t) {
  int i = blockIdx.x * 256 + threadIdx.x;
  if (i >= NSUP * DIN * DOUT) return;
  int s   = i >> 16;          // 512*128
  int rem = i & 65535;
  int k   = rem >> 7;
  int o   = rem & 127;
  b16t[(size_t)(s * DOUT + o) * DIN + k] = (unsigned short)bf16rne(w[i]);
}

// ---- Fused dropout + bf16 MFMA GEMM ----
// BM=64 rows, BN=256 (all cols), BK=64. 512 threads = 8 waves, wave grid 2x4:
// wave (wr,wc) owns rows wr*32..+31, cols wc*64..+63 -> 2x4 frags of 16x16x32.
__global__ __launch_bounds__(512) void gemm_mfma(
    const float* __restrict__ x, const unsigned short* __restrict__ b16t,
    unsigned short* __restrict__ pre16) {
  __shared__ unsigned short As[64 * 64];    // [row][k]  8KB
  __shared__ unsigned short Bs[256 * 64];   // [col][k] 32KB
  const int t    = threadIdx.x;
  const int lane = t & 63;
  const int w    = t >> 6;
  const int wr   = w >> 2;
  const int wc   = w & 3;
  const int m0   = blockIdx.x * 64;

  f32x4 acc[2][4];
#pragma unroll
  for (int i = 0; i < 2; ++i)
#pragma unroll
    for (int j = 0; j < 4; ++j) acc[i][j] = (f32x4){0.f, 0.f, 0.f, 0.f};

  const int arow  = t >> 3;          // 0..63
  const int ak8   = (t & 7) * 8;     // 0..56
  const int agrow = m0 + arow;

  for (int kc = 0; kc < DIN; kc += 64) {
    __syncthreads();
    // A stage: fp32 load + threefry dropout + bf16 pack, 8 elems/thread
    {
      union { uint32_t u[4]; short8 s; } pk;
      if (agrow < N_NODES) {
        const float4* src = reinterpret_cast<const float4*>(
            x + (size_t)agrow * DIN + kc + ak8);
        float4 v0 = src[0], v1 = src[1];
        float f[8] = {v0.x, v0.y, v0.z, v0.w, v1.x, v1.y, v1.z, v1.w};
        uint32_t base = (uint32_t)(agrow * DIN + kc + ak8);
#pragma unroll
        for (int q = 0; q < 8; ++q)
          f[q] = keep_mask(base + q) ? f[q] * 2.0f : 0.0f;
#pragma unroll
        for (int q = 0; q < 4; ++q) pk.u[q] = pack_bf16x2(f[2 * q], f[2 * q + 1]);
      } else {
#pragma unroll
        for (int q = 0; q < 4; ++q) pk.u[q] = 0u;
      }
      *reinterpret_cast<short8*>(&As[arow * 64 + ak8]) = pk.s;
    }
    // B stage: 256x64 bf16 from b16t, 4x16B per thread
#pragma unroll
    for (int i = 0; i < 4; ++i) {
      int c   = i * 512 + t;      // 0..2047
      int col = c >> 3;
      int k8  = (c & 7) * 8;
      short8 v = *reinterpret_cast<const short8*>(
          b16t + (size_t)col * DIN + kc + k8);
      *reinterpret_cast<short8*>(&Bs[col * 64 + k8]) = v;
    }
    __syncthreads();

    short8 af[2][2], bf[2][4];
#pragma unroll
    for (int mf = 0; mf < 2; ++mf)
#pragma unroll
      for (int kk = 0; kk < 2; ++kk) {
        int row = wr * 32 + mf * 16 + (lane & 15);
        af[mf][kk] = *reinterpret_cast<const short8*>(
            &As[row * 64 + kk * 32 + (lane >> 4) * 8]);
      }
#pragma unroll
    for (int kk = 0; kk < 2; ++kk)
#pragma unroll
      for (int nf = 0; nf < 4; ++nf) {
        int col = wc * 64 + nf * 16 + (lane & 15);
        bf[kk][nf] = *reinterpret_cast<const short8*>(
            &Bs[col * 64 + kk * 32 + (lane >> 4) * 8]);
      }
#pragma unroll
    for (int mf = 0; mf < 2; ++mf)
#pragma unroll
      for (int nf = 0; nf < 4; ++nf)
#pragma unroll
        for (int kk = 0; kk < 2; ++kk)
          acc[mf][nf] = __builtin_amdgcn_mfma_f32_16x16x32_bf16(
              af[mf][kk], bf[kk][nf], acc[mf][nf], 0, 0, 0);
  }

  // epilogue: C/D layout col=lane&15, row=(lane>>4)*4+q (m89-verified)
#pragma unroll
  for (int mf = 0; mf < 2; ++mf) {
    int rbase = m0 + wr * 32 + mf * 16 + ((lane >> 4) * 4);
#pragma unroll
    for (int nf = 0; nf < 4; ++nf) {
      int col = wc * 64 + nf * 16 + (lane & 15);
      int s = col >> 7, o = col & 127;
#pragma unroll
      for (int q = 0; q < 4; ++q) {
        int row = rbase + q;
        if (row < N_NODES)
          pre16[(size_t)(s * N_NODES + row) * DOUT + o] =
              (unsigned short)bf16rne(acc[mf][nf][q]);
      }
    }
  }
}

// ---- CSR build ----
__global__ __launch_bounds__(256) void count_k(
    const int* __restrict__ rows, int* __restrict__ cnt) {
  int i = blockIdx.x * 256 + threadIdx.x;
  if (i >= NSUP * EDGES) return;
  int s = (i >= EDGES) ? 1 : 0;
  atomicAdd(cnt + s * N_NODES + rows[i], 1);
}

__global__ __launch_bounds__(1024) void scanA(const int* __restrict__ cnt,
                                              int* __restrict__ row_start,
                                              int* __restrict__ bsum) {
  __shared__ int sm[1024];
  int t = threadIdx.x;
  int i = blockIdx.x * 1024 + t;
  int v = (i < NROWS) ? cnt[i] : 0;
  sm[t] = v;
  __syncthreads();
  for (int d = 1; d < 1024; d <<= 1) {
    int a = sm[t];
    int b = (t >= d) ? sm[t - d] : 0;
    __syncthreads();
    sm[t] = a + b;
    __syncthreads();
  }
  if (i < NROWS) row_start[i] = sm[t] - v;   // block-local exclusive
  if (t == 1023) bsum[blockIdx.x] = sm[t];
}

__global__ __launch_bounds__(128) void scanB(const int* __restrict__ bsum,
                                             int* __restrict__ boff,
                                             int* __restrict__ row_start) {
  __shared__ int sm[128];
  int t = threadIdx.x;
  int v = (t < 98) ? bsum[t] : 0;
  sm[t] = v;
  __syncthreads();
  for (int d = 1; d < 128; d <<= 1) {
    int a = sm[t];
    int b = (t >= d) ? sm[t - d] : 0;
    __syncthreads();
    sm[t] = a + b;
    __syncthreads();
  }
  if (t < 98) boff[t] = sm[t] - v;
  if (t == 0) row_start[NROWS] = NSUP * EDGES;
}

__global__ __launch_bounds__(1024) void scanC(int* __restrict__ row_start,
                                              const int* __restrict__ boff,
                                              int* __restrict__ cursor) {
  int i = blockIdx.x * 1024 + threadIdx.x;
  if (i >= NROWS) return;
  int v = row_start[i] + boff[blockIdx.x];
  row_start[i] = v;
  cursor[i] = v;
}

__global__ __launch_bounds__(256) void scatter_k(
    const int* __restrict__ rows, const int* __restrict__ cols,
    const float* __restrict__ vals, int* __restrict__ cursor,
    int2* __restrict__ pairs) {
  int i = blockIdx.x * 256 + threadIdx.x;
  if (i >= NSUP * EDGES) return;
  int s = (i >= EDGES) ? 1 : 0;
  int slot = atomicAdd(cursor + s * N_NODES + rows[i], 1);
  int2 pr;
  pr.x = s * N_NODES + cols[i];           // global row into pre16
  pr.y = __float_as_int(vals[i]);
  pairs[slot] = pr;
}

// ---- Pull SpMM + ReLU: 1 wave/row, lane owns cols {2l,2l+1}, 4x unrolled ----
__global__ __launch_bounds__(256) void spmm_pull(
    const int* __restrict__ row_start, const int2* __restrict__ pairs,
    const uint32_t* __restrict__ pre16, float* __restrict__ out) {
  int rid  = blockIdx.x * 4 + (threadIdx.x >> 6);
  int lane = threadIdx.x & 63;
  if (rid >= NROWS) return;
  int beg = row_start[rid];
  int end = row_start[rid + 1];
  float a0 = 0.f, a1 = 0.f;
  int j = beg;
  for (; j + 4 <= end; j += 4) {
    int2 p0 = pairs[j], p1 = pairs[j + 1], p2 = pairs[j + 2], p3 = pairs[j + 3];
    uint32_t q0 = pre16[(size_t)p0.x * 64 + lane];
    uint32_t q1 = pre16[(size_t)p1.x * 64 + lane];
    uint32_t q2 = pre16[(size_t)p2.x * 64 + lane];
    uint32_t q3 = pre16[(size_t)p3.x * 64 + lane];
    float v0 = __int_as_float(p0.y), v1 = __int_as_float(p1.y);
    float v2 = __int_as_float(p2.y), v3 = __int_as_float(p3.y);
    a0 += v0 * __uint_as_float(q0 << 16);
    a1 += v0 * __uint_as_float(q0 & 0xffff0000u);
    a0 += v1 * __uint_as_float(q1 << 16);
    a1 += v1 * __uint_as_float(q1 & 0xffff0000u);
    a0 += v2 * __uint_as_float(q2 << 16);
    a1 += v2 * __uint_as_float(q2 & 0xffff0000u);
    a0 += v3 * __uint_as_float(q3 << 16);
    a1 += v3 * __uint_as_float(q3 & 0xffff0000u);
  }
  for (; j < end; ++j) {
    int2 p = pairs[j];
    uint32_t q = pre16[(size_t)p.x * 64 + lane];
    float v = __int_as_float(p.y);
    a0 += v * __uint_as_float(q << 16);
    a1 += v * __uint_as_float(q & 0xffff0000u);
  }
  float2 o = make_float2(fmaxf(a0, 0.f), fmaxf(a1, 0.f));
  *reinterpret_cast<float2*>(out + (size_t)rid * DOUT + 2 * lane) = o;
}

extern "C" void kernel_launch(void* const* d_in, const int* in_sizes, int n_in,
                              void* d_out, int out_size, void* d_ws, size_t ws_size,
                              hipStream_t stream) {
  const float* x    = (const float*)d_in[0];
  const float* w    = (const float*)d_in[1];
  const int*   rows = (const int*)d_in[2];
  const int*   cols = (const int*)d_in[3];
  const float* vals = (const float*)d_in[4];
  float* out = (float*)d_out;

  // ws layout (u32 units)
  uint32_t* base      = (uint32_t*)d_ws;
  uint32_t* pre16     = base;                               // 6,400,000 u32 (bf16 x2)
  unsigned short* b16t = (unsigned short*)(base + 6400000); // 131072 u16 = 65536 u32
  int* cnt       = (int*)(base + 6400000 + 65536);          // 100,000
  int* row_start = cnt + 100000;                            // 100,004 (incl +1, pad)
  int* cursor    = row_start + 100004;                      // 100,000
  int* bsum      = cursor + 100000;                         // 128
  int* boff      = bsum + 128;                              // 128
  int2* pairs    = (int2*)(boff + 128);                     // 1,600,000 x 8B
  size_t need = ((size_t)6400000 + 65536 + 100000 + 100004 + 100000 + 128 + 128
                 + 3200000) * 4;
  if (ws_size < need) return;  // loud fail

  hipMemsetAsync(cnt, 0, 100000 * sizeof(int), stream);

  wcvt<<<(NSUP * DIN * DOUT + 255) / 256, 256, 0, stream>>>(w, b16t);

  const int mblocks = (N_NODES + 63) / 64;                  // 782
  gemm_mfma<<<mblocks, 512, 0, stream>>>(x, b16t, (unsigned short*)pre16);

  const int eblocks = (NSUP * EDGES + 255) / 256;           // 6250
  count_k<<<eblocks, 256, 0, stream>>>(rows, cnt);
  scanA<<<98, 1024, 0, stream>>>(cnt, row_start, bsum);
  scanB<<<1, 128, 0, stream>>>(bsum, boff, row_start);
  scanC<<<98, 1024, 0, stream>>>(row_start, boff, cursor);
  scatter_k<<<eblocks, 256, 0, stream>>>(rows, cols, vals, cursor, pairs);

  const int rblocks = (NROWS + 3) / 4;                      // 25000
  spmm_pull<<<rblocks, 256, 0, stream>>>(row_start, pairs, pre16, out);
}